// Round 23
// baseline (72.907 us; speedup 1.0000x reference)
//
#include <hip/hip_runtime.h>

// MPS classifier: logits[b,o] = (v/||v||)·cls[o] + log||v||,
//   v = head0(b) · M_1(b) · ... · M_783(b),  M_n = A_n + x[b,n]*(B_n - A_n).
// Chain associative; normalizations telescope.
//
// K1 (chunk_kernel): f16 chain, 2 lanes/sample, L=16 (C=49), in-place
//   (r22 semantics, verified), now with EXPLICIT GROUP PREFETCH: the 5
//   row-pair groups per site are fully unrolled with wA/wB uint4 ping-pong
//   -- group g+1's 5 ds_read_b128 issue before group g's blend+acc, so
//   ~100cy of pk-FMA covers the LDS latency. r22 measured VALU 46% + LDS
//   43% = serial sum (no overlap) at 12 waves/CU; this buys the overlap
//   with ILP instead of occupancy. acc[5][5] fresh per site, copied to p
//   (no source-level ping-pong of asm-tied arrays = no VGPR-32 collapse).
// K2 (combine_kernel, == r18/r22 verbatim, proven ~13.5us @ C=49,
//   race-clean): depth-7 DMA ring on 8 LDS slots, counted vmcnt(6),
//   lbuf pre-summed before staging. 512 x 64 blocks.

constexpr int Bsz = 2048;
constexpr int Nn  = 784;
constexpr int NS  = 783;
constexpr int LCH = 16;     // sites per chunk
constexpr int NCH = (NS + LCH - 1) / LCH;   // 49 chunks

// packed-f16 VOP3P on raw i32 registers (semantics proven r9-r22).
#define PKH_FMA(d, a, b, c) \
  asm("v_pk_fma_f16 %0, %1, %2, %3" : "=v"(d) : "v"(a), "v"(b), "v"(c))
#define PKH_ACC_LO(d, m, s) \
  asm("v_pk_fma_f16 %0, %1, %2, %0 op_sel:[0,0,0] op_sel_hi:[1,0,1]" \
      : "+v"(d) : "v"(m), "v"(s))
#define PKH_ACC_HI(d, m, s) \
  asm("v_pk_fma_f16 %0, %1, %2, %0 op_sel:[0,1,0] op_sel_hi:[1,1,1]" \
      : "+v"(d) : "v"(m), "v"(s))
#define PKH_MUL_LO(d, m, s) \
  asm("v_pk_mul_f16 %0, %1, %2 op_sel:[0,0] op_sel_hi:[1,0]" \
      : "=v"(d) : "v"(m), "v"(s))
// f16 (bits[15:0] of u) -> f32, opaque to the optimizer
#define CVT_H2F(f, u) asm("v_cvt_f32_f16 %0, %1" : "=v"(f) : "v"(u))

__device__ __forceinline__ unsigned short f2h_bits(float f) {
    union { _Float16 h; unsigned short u; } c;
    c.h = (_Float16)f;
    return c.u;
}
__device__ __forceinline__ float hlo(unsigned u) {
    union { unsigned short s; _Float16 h; } c;
    c.s = (unsigned short)(u & 0xffff);
    return (float)c.h;
}
__device__ __forceinline__ float hhi(unsigned u) {
    union { unsigned short s; _Float16 h; } c;
    c.s = (unsigned short)(u >> 16);
    return (float)c.h;
}

// ---------------- K1: f16 chain, in-place + group prefetch, L=16 ----------
__global__ __launch_bounds__(256, 4) void chunk_kernel(
    const float* __restrict__ x, const float* __restrict__ cores,
    unsigned* __restrict__ pbuf, float* __restrict__ lbuf) {
    __shared__ unsigned s_w[LCH * 100];  // per-site f16 {A,D} dwords
    __shared__ float    s_x[128 * 17];   // x slice, stride 17

    const int c   = blockIdx.y;
    const int n0  = 1 + c * LCH;
    const int n1  = min(n0 + LCH, Nn);
    const int ns  = n1 - n0;
    const int tid = (int)threadIdx.x;
    const int b0  = (int)blockIdx.x * 128;

    // stage + convert weights (fused repack): pair e=(k,s), s=(i*5+q)
    for (int e = tid; e < ns * 50; e += 256) {
        const int k = e / 50, s = e - k * 50;
        const int i = s / 5, q = s - i * 5;
        const float* g = cores + (size_t)(n0 - 1 + k) * 200 + i * 20 + 2 * q;
        const float a0 = g[0], a1 = g[1], bb0 = g[10], bb1 = g[11];
        const unsigned A = ((unsigned)f2h_bits(2.f * a1) << 16) | f2h_bits(2.f * a0);
        const unsigned D = ((unsigned)f2h_bits(2.f * (bb1 - a1)) << 16) |
                           f2h_bits(2.f * (bb0 - a0));
        s_w[k * 100 + 2 * s]     = A;
        s_w[k * 100 + 2 * s + 1] = D;
    }
    for (int e = tid; e < 128 * 16; e += 256) {
        const int bl = e >> 4, k = e & 15;
        if (k < ns) s_x[bl * 17 + k] = x[(size_t)(b0 + bl) * Nn + n0 + k];
    }
    __syncthreads();

    const int h = tid & 1;              // row-half owner
    const int u = tid >> 1;             // sample slot 0..127
    const int b = b0 + u;
    const float* __restrict__ xs = s_x + u * 17;

    unsigned p[5][5];                   // the ONLY chain-carried state
    {   // first site: P = 2*M (rows 5h..5h+4)
        const unsigned short xb = f2h_bits(xs[0]);
        const unsigned x2 = ((unsigned)xb << 16) | xb;
#pragma unroll
        for (int r = 0; r < 5; ++r)
#pragma unroll
            for (int q = 0; q < 5; ++q) {
                const unsigned A = s_w[(5 * h + r) * 10 + 2 * q];
                const unsigned D = s_w[(5 * h + r) * 10 + 2 * q + 1];
                PKH_FMA(p[r][q], D, x2, A);
            }
    }

// load 5 uint4 (one row-pair group) from w4[OFS..OFS+4] into W
#define GLOAD(W, OFS)                                   \
    { _Pragma("unroll")                                 \
      for (int t = 0; t < 5; ++t) W[t] = w4[(OFS) + t]; }

// blend group IP from W regs and accumulate rows 2IP/2IP+1 into acc
#define BLENDACC(W, IP)                                                 \
    {                                                                   \
        unsigned m[10];                                                 \
        _Pragma("unroll")                                               \
        for (int t = 0; t < 5; ++t) {                                   \
            PKH_FMA(m[2 * t],     W[t].y, x2, W[t].x);                  \
            PKH_FMA(m[2 * t + 1], W[t].w, x2, W[t].z);                  \
        }                                                               \
        _Pragma("unroll")                                               \
        for (int r = 0; r < 5; ++r) {                                   \
            if ((IP) == 0) {                                            \
                _Pragma("unroll")                                       \
                for (int q = 0; q < 5; ++q)                             \
                    PKH_MUL_LO(acc[r][q], m[q], p[r][0]);               \
            } else {                                                    \
                _Pragma("unroll")                                       \
                for (int q = 0; q < 5; ++q)                             \
                    PKH_ACC_LO(acc[r][q], m[q], p[r][(IP)]);            \
            }                                                           \
            _Pragma("unroll")                                           \
            for (int q = 0; q < 5; ++q)                                 \
                PKH_ACC_HI(acc[r][q], m[5 + q], p[r][(IP)]);            \
        }                                                               \
    }

    for (int k = 1; k < ns; ++k) {
        const unsigned short xb = f2h_bits(xs[k]);
        const unsigned x2 = ((unsigned)xb << 16) | xb;
        const uint4* w4 = (const uint4*)(s_w + k * 100);

        unsigned acc[5][5];
        uint4 wA[5], wB[5];
        GLOAD(wA, 0);                       // group 0
        GLOAD(wB, 5);  BLENDACC(wA, 0);     // pref g1, consume g0
        GLOAD(wA, 10); BLENDACC(wB, 1);     // pref g2, consume g1
        GLOAD(wB, 15); BLENDACC(wA, 2);     // pref g3, consume g2
        GLOAD(wA, 20); BLENDACC(wB, 3);     // pref g4, consume g3
        BLENDACC(wA, 4);                    // consume g4
#pragma unroll
        for (int r = 0; r < 5; ++r)
#pragma unroll
            for (int q = 0; q < 5; ++q) p[r][q] = acc[r][q];
    }
#undef GLOAD
#undef BLENDACC

    // Frobenius renorm (f32 accumulate, pair-reduce across the 2 lanes);
    // correct the 2^ns pre-scale in lbuf.
    float ss = 0.f;
#pragma unroll
    for (int r = 0; r < 5; ++r)
#pragma unroll
        for (int q = 0; q < 5; ++q) {
            const float lo = hlo(p[r][q]), hi = hhi(p[r][q]);
            ss = fmaf(lo, lo, ss);
            ss = fmaf(hi, hi, ss);
        }
    ss += __shfl_xor(ss, 1);
    ss = fmaxf(ss, 1e-30f);
    const float rin = rsqrtf(ss);
    if (h == 0)
        lbuf[(size_t)c * Bsz + b] = 0.5f * __logf(ss) - (float)ns * 0.69314718056f;

    // store packed f16 dwords: pbuf[(c*Bsz+b)*50 + (5h+r)*5 + q]
    unsigned* dst = pbuf + ((size_t)c * Bsz + b) * 50;
#pragma unroll
    for (int r = 0; r < 5; ++r)
#pragma unroll
        for (int q = 0; q < 5; ++q) {
            const float lo = hlo(p[r][q]) * rin;
            const float hi = hhi(p[r][q]) * rin;
            dst[(5 * h + r) * 5 + q] =
                ((unsigned)f2h_bits(hi) << 16) | f2h_bits(lo);
        }
}

// ---------------- K2: combine via explicit LDS pipeline (depth-7) ---------
__global__ __launch_bounds__(64, 1) void combine_kernel(
    const float* __restrict__ x, const float* __restrict__ core0,
    const float* __restrict__ cls, const unsigned* __restrict__ pbuf,
    const float* __restrict__ lbuf, float* __restrict__ out, int C) {
    __shared__ __align__(16) unsigned ring[8][256];

    const int tid   = (int)threadIdx.x;
    const int j     = tid & 15;
    const int jj    = (j < 10) ? j : 9;
    const int gbase = tid & 48;
    const int sl    = tid >> 4;               // sample slot 0..3
    const int b     = (int)blockIdx.x * 4 + sl;
    const int qoff  = jj >> 1;
    const unsigned sh = (unsigned)(jj & 1) * 16;

    // ---- v init + lbuf pre-sum (all global loads BEFORE staging) ----
    float v[10];
    const float x0 = x[(size_t)b * Nn];
#pragma unroll
    for (int i = 0; i < 10; ++i) {
        const float c0 = core0[i], c1 = core0[10 + i];
        v[i] = fmaf(x0, c1 - c0, c0);
    }
    float llog = 0.f;
    for (int cc = j; cc < C; cc += 16)
        llog += lbuf[(size_t)cc * Bsz + b];
    llog += __shfl_xor(llog, 1);
    llog += __shfl_xor(llog, 2);
    llog += __shfl_xor(llog, 4);
    llog += __shfl_xor(llog, 8);

    // ---- staging: lane stages dwords [l*4, l*4+4) of the wave's 200 ----
    const int flat = (tid * 4 <= 196) ? tid * 4 : 196;
    const unsigned* gsrc0 = pbuf + (size_t)blockIdx.x * 200 + flat;
    const size_t cstride = (size_t)Bsz * 50;

#define STAGE(cc)                                                          \
    __builtin_amdgcn_global_load_lds(                                      \
        (const __attribute__((address_space(1))) unsigned*)(gsrc0 +        \
            (size_t)(cc) * cstride),                                       \
        (__attribute__((address_space(3))) unsigned*)&ring[(cc) & 7][0],   \
        16, 0, 0)

#pragma unroll
    for (int d = 0; d < 7; ++d) STAGE(d);     // prologue: 7 in flight

    const int lbase = sl * 50 + qoff;
    for (int c = 0; c < C; ++c) {
        const int d = c & 7;
        if (c + 7 <= C - 1) {
            asm volatile("s_waitcnt vmcnt(6)" ::: "memory");
        } else {
            asm volatile("s_waitcnt vmcnt(0)" ::: "memory");
        }
        __builtin_amdgcn_sched_barrier(0);

        float acc = 0.f;
#pragma unroll
        for (int i = 0; i < 10; ++i) {
            unsigned ud = ring[d][lbase + i * 5] >> sh;
            float wv;
            CVT_H2F(wv, ud);
            acc = fmaf(v[i], wv, acc);
        }
        if (j >= 10) acc = 0.f;
        if ((c & 7) == 7 || c == C - 1) {     // deferred renorm
            float s = acc * acc;
            s += __shfl_xor(s, 1);
            s += __shfl_xor(s, 2);
            s += __shfl_xor(s, 4);
            s += __shfl_xor(s, 8);
            s = fmaxf(s, 1e-30f);
            llog += 0.5f * __logf(s);
            acc *= rsqrtf(s);
        }
#pragma unroll
        for (int i = 0; i < 10; ++i) v[i] = __shfl(acc, gbase + i);

        // refill: targets slot (c+7)&7 = (c-1)&7, consumed LAST iteration
        if (c + 7 < C) STAGE(c + 7);
    }
#undef STAGE

    if (j < 10) {
        float acc = llog;
#pragma unroll
        for (int i = 0; i < 10; ++i) acc = fmaf(v[i], cls[j * 10 + i], acc);
        out[(size_t)b * 10 + j] = acc;
    }
}

// ---------------- launch ----------------
extern "C" void kernel_launch(void* const* d_in, const int* in_sizes, int n_in,
                              void* d_out, int out_size, void* d_ws, size_t ws_size,
                              hipStream_t stream) {
    const float* x     = (const float*)d_in[0];
    const float* core0 = (const float*)d_in[1];
    const float* cores = (const float*)d_in[2];
    const float* cls   = (const float*)d_in[3];
    float* out = (float*)d_out;

    const int C = NCH;                          // 49
    unsigned* pbuf = (unsigned*)d_ws;           // C*Bsz*50 dwords = 20.1 MB
    float*    lbuf = (float*)(pbuf + (size_t)C * Bsz * 50);

    hipLaunchKernelGGL(chunk_kernel, dim3(Bsz / 128, C), dim3(256),
                       0, stream, x, cores, pbuf, lbuf);
    hipLaunchKernelGGL(combine_kernel, dim3(Bsz / 4), dim3(64),
                       0, stream, x, core0, cls, pbuf, lbuf, out, C);
}